// Round 1
// baseline (442.069 us; speedup 1.0000x reference)
//
#include <hip/hip_runtime.h>

// 3D Haar DWT, x: (2,32,64,128,128) f32 -> 8 subbands (2,32,32,64,64) f32,
// order LLL,LLH,LHL,LHH,HLL,HLH,HHL,HHH (letters = D,H,W; L=sum, H=diff, *K).
// Streaming: 256 MiB in, 256 MiB out. Loads stay nontemporal (don't pollute LLC);
// stores are REGULAR (cached) so the 256 MiB output — exactly LLC-sized — can be
// absorbed by L2/L3 and drain after the kernel's end timestamp (A/B vs nt-stores).
// One thread: 4 output q's for fixed (n,c,r,p): 8x16B nt-loads, 8x16B stores.

typedef float f32x4 __attribute__((ext_vector_type(4)));

namespace {
constexpr int SUBBAND = 2 * 32 * 32 * 64 * 64;       // 8,388,608 elems (fits int32)
constexpr int TOTAL_THREADS = 2 * 32 * 32 * 64 * 16; // n*c*r*p*(q-groups of 4)
}

__global__ __launch_bounds__(256) void dwt3d_haar_f32_cs(
    const float* __restrict__ x, float* __restrict__ out)
{
    int idx = blockIdx.x * blockDim.x + threadIdx.x;
    int qg = idx & 15;          // q = 4*qg .. 4*qg+3  (w = 8*qg .. 8*qg+7)
    int p  = (idx >> 4) & 63;   // output h
    int r  = (idx >> 10) & 31;  // output d
    int nc = idx >> 15;         // n*32 + c, [0,64)

    // input: (((nc*64 + d)*128 + h)*128 + w); d=2r(+1), h=2p(+1). Max offset 2^27 elems.
    const float* px = x + (((nc * 64 + 2 * r) * 128 + 2 * p) * 128 + 8 * qg);

    f32x4 A0 = __builtin_nontemporal_load((const f32x4*)(px));                 // d0 h0 w0..3
    f32x4 A1 = __builtin_nontemporal_load((const f32x4*)(px + 4));             // d0 h0 w4..7
    f32x4 B0 = __builtin_nontemporal_load((const f32x4*)(px + 128));           // d0 h1
    f32x4 B1 = __builtin_nontemporal_load((const f32x4*)(px + 132));
    f32x4 C0 = __builtin_nontemporal_load((const f32x4*)(px + 16384));         // d1 h0
    f32x4 C1 = __builtin_nontemporal_load((const f32x4*)(px + 16388));
    f32x4 D0 = __builtin_nontemporal_load((const f32x4*)(px + 16384 + 128));   // d1 h1
    f32x4 D1 = __builtin_nontemporal_load((const f32x4*)(px + 16384 + 132));

    // W stage: even/odd deinterleave across the 8 w's -> 4 q lanes, then sum/diff.
    // (shufflevector of whole dwords = register selection, no VALU cost)
    f32x4 ae = __builtin_shufflevector(A0, A1, 0, 2, 4, 6);
    f32x4 ao = __builtin_shufflevector(A0, A1, 1, 3, 5, 7);
    f32x4 be = __builtin_shufflevector(B0, B1, 0, 2, 4, 6);
    f32x4 bo = __builtin_shufflevector(B0, B1, 1, 3, 5, 7);
    f32x4 ce = __builtin_shufflevector(C0, C1, 0, 2, 4, 6);
    f32x4 co = __builtin_shufflevector(C0, C1, 1, 3, 5, 7);
    f32x4 de = __builtin_shufflevector(D0, D1, 0, 2, 4, 6);
    f32x4 do_ = __builtin_shufflevector(D0, D1, 1, 3, 5, 7);

    f32x4 sa = ae + ao, da = ae - ao;   // d0 h0
    f32x4 sb = be + bo, db = be - bo;   // d0 h1
    f32x4 sc = ce + co, dc = ce - co;   // d1 h0
    f32x4 sd = de + do_, dd = de - do_; // d1 h1

    // H stage
    f32x4 sLs = sa + sb, sHs = sa - sb; // d0 w-low
    f32x4 sLd = da + db, sHd = da - db; // d0 w-high
    f32x4 tLs = sc + sd, tHs = sc - sd; // d1 w-low
    f32x4 tLd = dc + dd, tHd = dc - dd; // d1 w-high

    const float K = 0.35355339059327373f; // (1/sqrt(2))^3
    // out: s*SUBBAND + (((nc*32 + r)*64 + p)*64 + q); max s*SUBBAND+... = 2^26 elems, int ok
    float* po = out + (((nc * 32 + r) * 64 + p) * 64 + 4 * qg);

    // D stage + scale; subband bits (D,H,W) = (s>>2, s>>1&1, s&1).
    // Regular (cached) stores: let L2/LLC absorb the write burst.
    *(f32x4*)(po + 0 * SUBBAND) = K * (sLs + tLs); // LLL
    *(f32x4*)(po + 1 * SUBBAND) = K * (sLd + tLd); // LLH
    *(f32x4*)(po + 2 * SUBBAND) = K * (sHs + tHs); // LHL
    *(f32x4*)(po + 3 * SUBBAND) = K * (sHd + tHd); // LHH
    *(f32x4*)(po + 4 * SUBBAND) = K * (sLs - tLs); // HLL
    *(f32x4*)(po + 5 * SUBBAND) = K * (sLd - tLd); // HLH
    *(f32x4*)(po + 6 * SUBBAND) = K * (sHs - tHs); // HHL
    *(f32x4*)(po + 7 * SUBBAND) = K * (sHd - tHd); // HHH
}

extern "C" void kernel_launch(void* const* d_in, const int* in_sizes, int n_in,
                              void* d_out, int out_size, void* d_ws, size_t ws_size,
                              hipStream_t stream) {
    const float* x = (const float*)d_in[0];  // (2,32,64,128,128) f32
    float* out = (float*)d_out;              // 8 subbands concatenated, f32
    dwt3d_haar_f32_cs<<<TOTAL_THREADS / 256, 256, 0, stream>>>(x, out);
}

// Round 2
// 440.989 us; speedup vs baseline: 1.0024x; 1.0024x over previous
//
#include <hip/hip_runtime.h>

// 3D Haar DWT, x: (2,32,64,128,128) f32 -> 8 subbands (2,32,32,64,64) f32,
// order LLL,LLH,LHL,LHH,HLL,HLH,HHL,HHH (letters = D,H,W; L=sum, H=diff, *K).
// Streaming: 256 MiB in, 256 MiB out, zero reuse -> nontemporal loads/stores.
//
// R2 change (lane-contiguous loads): previous layout had lane qg load 16B at
// w=8qg (stride 32B) so each 64B line was requested by TWO load instructions
// (2 half-line L2 requests per line). Now lane qg loads 16B at w=4qg: each
// load instruction covers a contiguous 256B span per 16-lane group -> every
// 64B line is requested exactly once, full-line. Thread owns w {4qg..4qg+3}
// and {64+4qg..67+4qg} -> q {2qg,2qg+1} and {32+2qg,33+2qg}; stores become
// 16x8B (f32x2), each wave-store a run of full 64B lines (unchanged count).

typedef float f32x4 __attribute__((ext_vector_type(4)));
typedef float f32x2 __attribute__((ext_vector_type(2)));

namespace {
constexpr int SUBBAND = 2 * 32 * 32 * 64 * 64;       // 8,388,608 elems
constexpr int TOTAL_THREADS = 2 * 32 * 32 * 64 * 16; // n*c*r*p*(16 lanes over w)
constexpr float K = 0.35355339059327373f;            // (1/sqrt(2))^3
}

// One 16B chunk (4 consecutive w = 2 output q's) of 4 input rows
// (d0h0, d0h1, d1h0, d1h1) -> 8 subband f32x2 stores at po.
__device__ __forceinline__ void dwt_chunk(f32x4 a, f32x4 b, f32x4 c, f32x4 d,
                                          float* po)
{
    // W stage: even/odd within the 16B chunk.
    f32x2 ae = __builtin_shufflevector(a, a, 0, 2), ao = __builtin_shufflevector(a, a, 1, 3);
    f32x2 be = __builtin_shufflevector(b, b, 0, 2), bo = __builtin_shufflevector(b, b, 1, 3);
    f32x2 ce = __builtin_shufflevector(c, c, 0, 2), co = __builtin_shufflevector(c, c, 1, 3);
    f32x2 de = __builtin_shufflevector(d, d, 0, 2), do_ = __builtin_shufflevector(d, d, 1, 3);

    f32x2 sa = ae + ao, da = ae - ao;   // d0 h0
    f32x2 sb = be + bo, db = be - bo;   // d0 h1
    f32x2 sc = ce + co, dc = ce - co;   // d1 h0
    f32x2 sd = de + do_, dd = de - do_; // d1 h1

    // H stage
    f32x2 sLs = sa + sb, sHs = sa - sb; // d0 w-low
    f32x2 sLd = da + db, sHd = da - db; // d0 w-high
    f32x2 tLs = sc + sd, tHs = sc - sd; // d1 w-low
    f32x2 tLd = dc + dd, tHd = dc - dd; // d1 w-high

    // D stage + scale; subband bits (D,H,W) = (s>>2, s>>1&1, s&1)
    __builtin_nontemporal_store(K * (sLs + tLs), (f32x2*)(po + 0 * SUBBAND)); // LLL
    __builtin_nontemporal_store(K * (sLd + tLd), (f32x2*)(po + 1 * SUBBAND)); // LLH
    __builtin_nontemporal_store(K * (sHs + tHs), (f32x2*)(po + 2 * SUBBAND)); // LHL
    __builtin_nontemporal_store(K * (sHd + tHd), (f32x2*)(po + 3 * SUBBAND)); // LHH
    __builtin_nontemporal_store(K * (sLs - tLs), (f32x2*)(po + 4 * SUBBAND)); // HLL
    __builtin_nontemporal_store(K * (sLd - tLd), (f32x2*)(po + 5 * SUBBAND)); // HLH
    __builtin_nontemporal_store(K * (sHs - tHs), (f32x2*)(po + 6 * SUBBAND)); // HHL
    __builtin_nontemporal_store(K * (sHd - tHd), (f32x2*)(po + 7 * SUBBAND)); // HHH
}

__global__ __launch_bounds__(256) void dwt3d_haar_f32_lc(
    const float* __restrict__ x, float* __restrict__ out)
{
    int idx = blockIdx.x * blockDim.x + threadIdx.x;
    int qg = idx & 15;          // lane's w-chunk: w = 4qg.. and 64+4qg..
    int p  = (idx >> 4) & 63;   // output h
    int r  = (idx >> 10) & 31;  // output d
    int nc = idx >> 15;         // n*32 + c, [0,64)

    // input: (((nc*64 + d)*128 + h)*128 + w); d=2r(+1), h=2p(+1). Max offset 2^27 elems.
    const float* px = x + (((nc * 64 + 2 * r) * 128 + 2 * p) * 128 + 4 * qg);

    // E chunks: bytes [16qg, 16qg+16) of each row -> lane-contiguous across wave.
    f32x4 Ea = __builtin_nontemporal_load((const f32x4*)(px));          // d0 h0
    f32x4 Eb = __builtin_nontemporal_load((const f32x4*)(px + 128));    // d0 h1
    f32x4 Ec = __builtin_nontemporal_load((const f32x4*)(px + 16384));  // d1 h0
    f32x4 Ed = __builtin_nontemporal_load((const f32x4*)(px + 16512));  // d1 h1
    // F chunks: second half of the row (w = 64 + 4qg ..).
    f32x4 Fa = __builtin_nontemporal_load((const f32x4*)(px + 64));
    f32x4 Fb = __builtin_nontemporal_load((const f32x4*)(px + 192));
    f32x4 Fc = __builtin_nontemporal_load((const f32x4*)(px + 16448));
    f32x4 Fd = __builtin_nontemporal_load((const f32x4*)(px + 16576));

    // out: s*SUBBAND + (((nc*32 + r)*64 + p)*64 + q)
    float* po = out + (((nc * 32 + r) * 64 + p) * 64 + 2 * qg);

    dwt_chunk(Ea, Eb, Ec, Ed, po);      // q = 2qg, 2qg+1
    dwt_chunk(Fa, Fb, Fc, Fd, po + 32); // q = 32+2qg, 33+2qg
}

extern "C" void kernel_launch(void* const* d_in, const int* in_sizes, int n_in,
                              void* d_out, int out_size, void* d_ws, size_t ws_size,
                              hipStream_t stream) {
    const float* x = (const float*)d_in[0];  // (2,32,64,128,128) f32
    float* out = (float*)d_out;              // 8 subbands concatenated, f32
    dwt3d_haar_f32_lc<<<TOTAL_THREADS / 256, 256, 0, stream>>>(x, out);
}